// Round 2
// baseline (387.052 us; speedup 1.0000x reference)
//
#include <hip/hip_runtime.h>
#include <math.h>

#define N_NODES 100000
#define N_EDGES 3200000
#define F_IN    256
#define D_OUT   128

typedef __attribute__((ext_vector_type(8))) short short8;
typedef __attribute__((ext_vector_type(4))) float f32x4;

__device__ __forceinline__ unsigned short f2bf(float f) {
    unsigned u = __float_as_uint(f);
    unsigned r = (u + 0x7FFFu + ((u >> 16) & 1u)) >> 16;   // RNE
    return (unsigned short)r;
}

__device__ __forceinline__ float dot4(f32x4 a, f32x4 b) {
    return a.x * b.x + a.y * b.y + a.z * b.z + a.w * b.w;
}

// signed byte k (0..3) of u, as float
__device__ __forceinline__ float sb(unsigned u, int k) {
    return (float)((int)(u << ((3 - k) * 8)) >> 24);
}

// ---------------------------------------------------------------------------
// Kernel A: 256 blocks x 128 threads. Block kk:
//   - kbT[n][kk] = bf16(kern[kk][n])  (coalesced read of kern row kk)
//   - wave 0 computes v1[kk] = W1[kk]@w2, v2[kk] = W1[kk]@w3
// ---------------------------------------------------------------------------
__global__ __launch_bounds__(128) void prep_kernel(
    const float* __restrict__ W1, const float* __restrict__ w2,
    const float* __restrict__ w3, const float* __restrict__ kern,
    float* __restrict__ v1, float* __restrict__ v2,
    unsigned short* __restrict__ kbT) {
    const int kk  = blockIdx.x;    // 0..255
    const int tid = threadIdx.x;   // 0..127
    kbT[(size_t)tid * F_IN + kk] = f2bf(kern[(size_t)kk * D_OUT + tid]);
    if (tid < 64) {
        const float* wr = W1 + (size_t)kk * D_OUT;
        float a = wr[tid], b = wr[tid + 64];
        float s1 = a * w2[tid] + b * w2[tid + 64];
        float s2 = a * w3[tid] + b * w3[tid + 64];
#pragma unroll
        for (int o = 32; o > 0; o >>= 1) {
            s1 += __shfl_xor(s1, o);
            s2 += __shfl_xor(s2, o);
        }
        if (tid == 0) { v1[kk] = s1; v2[kk] = s2; }
    }
}

// ---------------------------------------------------------------------------
// Kernel B: CSR row pointers via binary search over sorted edge_row.
// ---------------------------------------------------------------------------
__global__ void row_ptr_kernel(const int* __restrict__ edge_row,
                               int* __restrict__ row_ptr) {
    int r = blockIdx.x * blockDim.x + threadIdx.x;
    if (r > N_NODES) return;
    int lo = 0, hi = N_EDGES;
    while (lo < hi) {
        int mid = (lo + hi) >> 1;
        if (edge_row[mid] < r) lo = mid + 1; else hi = mid;
    }
    row_ptr[r] = lo;
}

// ---------------------------------------------------------------------------
// Kernel C: bf16 MFMA GEMM; epilogue quantizes value rows to int8 with
// per-row absmax scale (valq + scale). Fused fp32 sa1/sa2.
// ---------------------------------------------------------------------------
__global__ __launch_bounds__(256) void gemm_sa_kernel(
    const float* __restrict__ x, const unsigned short* __restrict__ kbT,
    const float* __restrict__ v1, const float* __restrict__ v2,
    const float* __restrict__ b2p, const float* __restrict__ b3p,
    signed char* __restrict__ valq, float* __restrict__ scale,
    float* __restrict__ sa1, float* __restrict__ sa2) {
    const int wid = blockIdx.x * 4 + (threadIdx.x >> 6);
    const int m_base = wid * 32;
    if (m_base >= N_NODES) return;
    const int lane = threadIdx.x & 63;
    const int r = lane & 15;
    const int q = lane >> 4;

    const f32x4* x0 = (const f32x4*)(x + (size_t)(m_base + r) * F_IN + q * 8);
    const f32x4* x1 = (const f32x4*)(x + (size_t)(m_base + 16 + r) * F_IN + q * 8);

    f32x4 acc[2][8];
#pragma unroll
    for (int t = 0; t < 2; ++t)
#pragma unroll
        for (int nt = 0; nt < 8; ++nt) acc[t][nt] = (f32x4)(0.f);
    float s1a = 0.f, s1b = 0.f, s2a = 0.f, s2b = 0.f;

#pragma unroll 2
    for (int s = 0; s < 8; ++s) {            // K-steps of 32
        f32x4 p00 = __builtin_nontemporal_load(x0 + s * 8);
        f32x4 p01 = __builtin_nontemporal_load(x0 + s * 8 + 1);
        f32x4 p10 = __builtin_nontemporal_load(x1 + s * 8);
        f32x4 p11 = __builtin_nontemporal_load(x1 + s * 8 + 1);
        const f32x4* vp1 = (const f32x4*)(v1 + s * 32 + q * 8);
        const f32x4* vp2 = (const f32x4*)(v2 + s * 32 + q * 8);
        f32x4 va = vp1[0], vb = vp1[1], vc = vp2[0], vd = vp2[1];
        s1a += dot4(p00, va) + dot4(p01, vb);
        s2a += dot4(p00, vc) + dot4(p01, vd);
        s1b += dot4(p10, va) + dot4(p11, vb);
        s2b += dot4(p10, vc) + dot4(p11, vd);

        short8 a0, a1;
        a0[0] = (short)f2bf(p00.x); a0[1] = (short)f2bf(p00.y);
        a0[2] = (short)f2bf(p00.z); a0[3] = (short)f2bf(p00.w);
        a0[4] = (short)f2bf(p01.x); a0[5] = (short)f2bf(p01.y);
        a0[6] = (short)f2bf(p01.z); a0[7] = (short)f2bf(p01.w);
        a1[0] = (short)f2bf(p10.x); a1[1] = (short)f2bf(p10.y);
        a1[2] = (short)f2bf(p10.z); a1[3] = (short)f2bf(p10.w);
        a1[4] = (short)f2bf(p11.x); a1[5] = (short)f2bf(p11.y);
        a1[6] = (short)f2bf(p11.z); a1[7] = (short)f2bf(p11.w);

#pragma unroll
        for (int nt = 0; nt < 8; ++nt) {
            const short8 b = *(const short8*)(kbT + (size_t)(nt * 16 + r) * F_IN
                                              + s * 32 + q * 8);
            acc[0][nt] = __builtin_amdgcn_mfma_f32_16x16x32_bf16(a0, b, acc[0][nt], 0, 0, 0);
            acc[1][nt] = __builtin_amdgcn_mfma_f32_16x16x32_bf16(a1, b, acc[1][nt], 0, 0, 0);
        }
    }

    s1a += __shfl_xor(s1a, 16); s1a += __shfl_xor(s1a, 32);
    s1b += __shfl_xor(s1b, 16); s1b += __shfl_xor(s1b, 32);
    s2a += __shfl_xor(s2a, 16); s2a += __shfl_xor(s2a, 32);
    s2b += __shfl_xor(s2b, 16); s2b += __shfl_xor(s2b, 32);
    if (q == 0) {
        float bb2 = b2p[0], bb3 = b3p[0];
        sa1[m_base + r]      = s1a + bb2;
        sa1[m_base + 16 + r] = s1b + bb2;
        sa2[m_base + r]      = s2a + bb3;
        sa2[m_base + 16 + r] = s2b + bb3;
    }

    // epilogue: per-row absmax -> int8 quantize + scale store
#pragma unroll
    for (int t = 0; t < 2; ++t)
#pragma unroll
        for (int reg = 0; reg < 4; ++reg) {
            float m = 0.f;
#pragma unroll
            for (int nt = 0; nt < 8; ++nt) m = fmaxf(m, fabsf(acc[t][nt][reg]));
            m = fmaxf(m, __shfl_xor(m, 1));
            m = fmaxf(m, __shfl_xor(m, 2));
            m = fmaxf(m, __shfl_xor(m, 4));
            m = fmaxf(m, __shfl_xor(m, 8));
            const int row = m_base + t * 16 + q * 4 + reg;
            const float inv = m > 0.f ? 127.f / m : 0.f;
            if (r == 0) scale[row] = m * (1.f / 127.f);
#pragma unroll
            for (int nt = 0; nt < 8; ++nt) {
                int iq = (int)rintf(acc[t][nt][reg] * inv);
                valq[(size_t)row * D_OUT + nt * 16 + r] = (signed char)iq;
            }
        }
}

// ---------------------------------------------------------------------------
// Kernel D: fused softmax + SpMM. ONE 16-LANE GROUP PER ROW, 4 rows/wave.
//  - All per-edge scalar loads (edge_col/adj/sa2/scale) are same-address
//    within the group -> HW broadcast, no __shfl anywhere.
//  - All 16 lanes redundantly compute the edge scalar (t/leaky/exp/w): the
//    softmax denominator is then held identically by every lane (no
//    reduction), and each lane owns 8 output columns (no acc reduction).
//  - 2-stage software pipeline, unroll 4: next block's (c,a) prefetched
//    while current block's 12 gathers (4x {sa2,scale,valq}) are in flight
//    -> ~16 outstanding gathers per wave vs ~4 before.
// ---------------------------------------------------------------------------
__global__ __launch_bounds__(256) void attn_agg_kernel(
    const int* __restrict__ row_ptr, const int* __restrict__ edge_col,
    const float* __restrict__ adj, const float* __restrict__ sa1,
    const float* __restrict__ sa2, const signed char* __restrict__ valq,
    const float* __restrict__ scale, const float* __restrict__ bias,
    float* __restrict__ out) {
    const int lane = threadIdx.x & 63;
    const int g    = lane >> 4;
    const int r    = lane & 15;
    const int row  = blockIdx.x * 16 + ((threadIdx.x >> 6) << 2) + g;

    const int s    = row_ptr[row];
    const int cnt  = row_ptr[row + 1] - s;
    const float sa1r = sa1[row];
    const signed char* vbase = valq + r * 8;

    float acc[8];
#pragma unroll
    for (int j = 0; j < 8; ++j) acc[j] = 0.f;
    float sum = 0.f;

    const int n4 = cnt & ~3;

    // ---- pipelined main loop over blocks of 4 edges ----
    int   c0, c1, c2, c3;
    float a0, a1, a2, a3;
    bool act = (0 < n4);
    if (act) {
        c0 = __builtin_nontemporal_load(edge_col + s);
        c1 = __builtin_nontemporal_load(edge_col + s + 1);
        c2 = __builtin_nontemporal_load(edge_col + s + 2);
        c3 = __builtin_nontemporal_load(edge_col + s + 3);
        a0 = __builtin_nontemporal_load(adj + s);
        a1 = __builtin_nontemporal_load(adj + s + 1);
        a2 = __builtin_nontemporal_load(adj + s + 2);
        a3 = __builtin_nontemporal_load(adj + s + 3);
    }
    int i = 0;
    while (__any(act)) {
        const int  inext = i + 4;
        const bool actn  = (inext < n4);
        int   d0 = 0, d1 = 0, d2 = 0, d3 = 0;
        float e0 = 0, e1 = 0, e2 = 0, e3 = 0;
        if (actn) {
            d0 = __builtin_nontemporal_load(edge_col + s + inext);
            d1 = __builtin_nontemporal_load(edge_col + s + inext + 1);
            d2 = __builtin_nontemporal_load(edge_col + s + inext + 2);
            d3 = __builtin_nontemporal_load(edge_col + s + inext + 3);
            e0 = __builtin_nontemporal_load(adj + s + inext);
            e1 = __builtin_nontemporal_load(adj + s + inext + 1);
            e2 = __builtin_nontemporal_load(adj + s + inext + 2);
            e3 = __builtin_nontemporal_load(adj + s + inext + 3);
        }
        if (act) {
            const int cc[4] = {c0, c1, c2, c3};
            const float aa[4] = {a0, a1, a2, a3};
#pragma unroll
            for (int j = 0; j < 4; ++j) {
                const int cj = cc[j];
                float t = aa[j] * (sa1r + sa2[cj]);
                t = fmaxf(t, 0.2f * t);              // leaky_relu(0.2)
                const float ex = __expf(t);
                sum += ex;
                const float w = ex * scale[cj];      // fold dequant scale
                const uint2 p = *(const uint2*)(vbase + (size_t)cj * D_OUT);
                acc[0] += w * sb(p.x, 0); acc[1] += w * sb(p.x, 1);
                acc[2] += w * sb(p.x, 2); acc[3] += w * sb(p.x, 3);
                acc[4] += w * sb(p.y, 0); acc[5] += w * sb(p.y, 1);
                acc[6] += w * sb(p.y, 2); acc[7] += w * sb(p.y, 3);
            }
        }
        c0 = d0; c1 = d1; c2 = d2; c3 = d3;
        a0 = e0; a1 = e1; a2 = e2; a3 = e3;
        i = inext;
        act = actn;
    }

    // ---- tail: 0..3 edges ----
    int i2 = n4;
    while (__any(i2 < cnt)) {
        if (i2 < cnt) {
            const int e = s + i2;
            const int cj = __builtin_nontemporal_load(edge_col + e);
            float t = __builtin_nontemporal_load(adj + e) * (sa1r + sa2[cj]);
            t = fmaxf(t, 0.2f * t);
            const float ex = __expf(t);
            sum += ex;
            const float w = ex * scale[cj];
            const uint2 p = *(const uint2*)(vbase + (size_t)cj * D_OUT);
            acc[0] += w * sb(p.x, 0); acc[1] += w * sb(p.x, 1);
            acc[2] += w * sb(p.x, 2); acc[3] += w * sb(p.x, 3);
            acc[4] += w * sb(p.y, 0); acc[5] += w * sb(p.y, 1);
            acc[6] += w * sb(p.y, 2); acc[7] += w * sb(p.y, 3);
        }
        ++i2;
    }

    // every lane of the group holds the full denominator -> no reduction
    const float inv = sum > 0.f ? 1.f / sum : 1.f;

    const f32x4* bp = (const f32x4*)(bias + (size_t)row * D_OUT + r * 8);
    f32x4 b0 = __builtin_nontemporal_load(bp);
    f32x4 b1 = __builtin_nontemporal_load(bp + 1);
    f32x4 r0, r1;
    r0.x = acc[0] * inv + b0.x; r0.y = acc[1] * inv + b0.y;
    r0.z = acc[2] * inv + b0.z; r0.w = acc[3] * inv + b0.w;
    r1.x = acc[4] * inv + b1.x; r1.y = acc[5] * inv + b1.y;
    r1.z = acc[6] * inv + b1.z; r1.w = acc[7] * inv + b1.w;
    f32x4* op = (f32x4*)(out + (size_t)row * D_OUT + r * 8);
    __builtin_nontemporal_store(r0, op);
    __builtin_nontemporal_store(r1, op + 1);
}

// ---------------------------------------------------------------------------
extern "C" void kernel_launch(void* const* d_in, const int* in_sizes, int n_in,
                              void* d_out, int out_size, void* d_ws,
                              size_t ws_size, hipStream_t stream) {
    const float* x        = (const float*)d_in[0];
    const float* adj      = (const float*)d_in[1];
    const float* W1       = (const float*)d_in[2];
    const float* w2       = (const float*)d_in[3];
    const float* b2       = (const float*)d_in[4];
    const float* w3       = (const float*)d_in[5];
    const float* b3       = (const float*)d_in[6];
    const float* kern     = (const float*)d_in[7];
    const float* bias     = (const float*)d_in[8];
    const int*   edge_row = (const int*)d_in[9];
    const int*   edge_col = (const int*)d_in[10];
    float* out = (float*)d_out;

    signed char* valq = (signed char*)d_ws;                  // N*128 int8
    float* scale = (float*)(valq + (size_t)N_NODES * D_OUT); // N fp32
    float* sa1 = scale + N_NODES;                            // N fp32
    float* sa2 = sa1 + N_NODES;                              // N fp32
    int*   row_ptr = (int*)(sa2 + N_NODES);                  // N+1 (pad)
    float* v1 = (float*)(row_ptr + N_NODES + 4);             // 256
    float* v2 = v1 + F_IN;                                   // 256
    unsigned short* kbT = (unsigned short*)(v2 + F_IN);      // 128*256 bf16

    hipLaunchKernelGGL(prep_kernel, dim3(256), dim3(128), 0, stream,
                       W1, w2, w3, kern, v1, v2, kbT);
    hipLaunchKernelGGL(row_ptr_kernel, dim3((N_NODES + 1 + 255) / 256),
                       dim3(256), 0, stream, edge_row, row_ptr);
    hipLaunchKernelGGL(gemm_sa_kernel, dim3((N_NODES / 32 + 3) / 4), dim3(256),
                       0, stream, x, kbT, v1, v2, b2, b3, valq, scale, sa1,
                       sa2);
    hipLaunchKernelGGL(attn_agg_kernel, dim3(N_NODES / 16), dim3(256), 0,
                       stream, row_ptr, edge_col, adj, sa1, sa2, valq, scale,
                       bias, out);
}

// Round 3
// 354.158 us; speedup vs baseline: 1.0929x; 1.0929x over previous
//
#include <hip/hip_runtime.h>
#include <math.h>

#define N_NODES 100000
#define N_EDGES 3200000
#define F_IN    256
#define D_OUT   128

typedef __attribute__((ext_vector_type(8))) short short8;
typedef __attribute__((ext_vector_type(4))) float f32x4;

__device__ __forceinline__ unsigned short f2bf(float f) {
    unsigned u = __float_as_uint(f);
    unsigned r = (u + 0x7FFFu + ((u >> 16) & 1u)) >> 16;   // RNE
    return (unsigned short)r;
}

__device__ __forceinline__ float dot4(f32x4 a, f32x4 b) {
    return a.x * b.x + a.y * b.y + a.z * b.z + a.w * b.w;
}

// unsigned byte k (0..3) of u, as float -> v_cvt_f32_ubyteN
__device__ __forceinline__ float ub(unsigned u, int k) {
    return (float)((u >> (k * 8)) & 0xffu);
}

// ---------------------------------------------------------------------------
// Kernel A: 256 blocks x 128 threads. Block kk:
//   - kbT[n][kk] = bf16(kern[kk][n])  (coalesced read of kern row kk)
//   - wave 0 computes v1[kk] = W1[kk]@w2, v2[kk] = W1[kk]@w3
// ---------------------------------------------------------------------------
__global__ __launch_bounds__(128) void prep_kernel(
    const float* __restrict__ W1, const float* __restrict__ w2,
    const float* __restrict__ w3, const float* __restrict__ kern,
    float* __restrict__ v1, float* __restrict__ v2,
    unsigned short* __restrict__ kbT) {
    const int kk  = blockIdx.x;    // 0..255
    const int tid = threadIdx.x;   // 0..127
    kbT[(size_t)tid * F_IN + kk] = f2bf(kern[(size_t)kk * D_OUT + tid]);
    if (tid < 64) {
        const float* wr = W1 + (size_t)kk * D_OUT;
        float a = wr[tid], b = wr[tid + 64];
        float s1 = a * w2[tid] + b * w2[tid + 64];
        float s2 = a * w3[tid] + b * w3[tid + 64];
#pragma unroll
        for (int o = 32; o > 0; o >>= 1) {
            s1 += __shfl_xor(s1, o);
            s2 += __shfl_xor(s2, o);
        }
        if (tid == 0) { v1[kk] = s1; v2[kk] = s2; }
    }
}

// ---------------------------------------------------------------------------
// Kernel B: CSR row pointers via binary search over sorted edge_row.
// ---------------------------------------------------------------------------
__global__ void row_ptr_kernel(const int* __restrict__ edge_row,
                               int* __restrict__ row_ptr) {
    int r = blockIdx.x * blockDim.x + threadIdx.x;
    if (r > N_NODES) return;
    int lo = 0, hi = N_EDGES;
    while (lo < hi) {
        int mid = (lo + hi) >> 1;
        if (edge_row[mid] < r) lo = mid + 1; else hi = mid;
    }
    row_ptr[r] = lo;
}

// ---------------------------------------------------------------------------
// Kernel C: bf16 MFMA GEMM; epilogue quantizes value rows to UNSIGNED int8
// (bias +128) with per-row absmax scale; writes fused szc[row]=(sa2,scale)
// so the attn kernel gathers both with one 8B load.
// ---------------------------------------------------------------------------
__global__ __launch_bounds__(256) void gemm_sa_kernel(
    const float* __restrict__ x, const unsigned short* __restrict__ kbT,
    const float* __restrict__ v1, const float* __restrict__ v2,
    const float* __restrict__ b2p, const float* __restrict__ b3p,
    unsigned char* __restrict__ valq, float2* __restrict__ szc,
    float* __restrict__ sa1) {
    const int wid = blockIdx.x * 4 + (threadIdx.x >> 6);
    const int m_base = wid * 32;
    if (m_base >= N_NODES) return;
    const int lane = threadIdx.x & 63;
    const int r = lane & 15;
    const int q = lane >> 4;

    const f32x4* x0 = (const f32x4*)(x + (size_t)(m_base + r) * F_IN + q * 8);
    const f32x4* x1 = (const f32x4*)(x + (size_t)(m_base + 16 + r) * F_IN + q * 8);

    f32x4 acc[2][8];
#pragma unroll
    for (int t = 0; t < 2; ++t)
#pragma unroll
        for (int nt = 0; nt < 8; ++nt) acc[t][nt] = (f32x4)(0.f);
    float s1a = 0.f, s1b = 0.f, s2a = 0.f, s2b = 0.f;

#pragma unroll 2
    for (int s = 0; s < 8; ++s) {            // K-steps of 32
        f32x4 p00 = __builtin_nontemporal_load(x0 + s * 8);
        f32x4 p01 = __builtin_nontemporal_load(x0 + s * 8 + 1);
        f32x4 p10 = __builtin_nontemporal_load(x1 + s * 8);
        f32x4 p11 = __builtin_nontemporal_load(x1 + s * 8 + 1);
        const f32x4* vp1 = (const f32x4*)(v1 + s * 32 + q * 8);
        const f32x4* vp2 = (const f32x4*)(v2 + s * 32 + q * 8);
        f32x4 va = vp1[0], vb = vp1[1], vc = vp2[0], vd = vp2[1];
        s1a += dot4(p00, va) + dot4(p01, vb);
        s2a += dot4(p00, vc) + dot4(p01, vd);
        s1b += dot4(p10, va) + dot4(p11, vb);
        s2b += dot4(p10, vc) + dot4(p11, vd);

        short8 a0, a1;
        a0[0] = (short)f2bf(p00.x); a0[1] = (short)f2bf(p00.y);
        a0[2] = (short)f2bf(p00.z); a0[3] = (short)f2bf(p00.w);
        a0[4] = (short)f2bf(p01.x); a0[5] = (short)f2bf(p01.y);
        a0[6] = (short)f2bf(p01.z); a0[7] = (short)f2bf(p01.w);
        a1[0] = (short)f2bf(p10.x); a1[1] = (short)f2bf(p10.y);
        a1[2] = (short)f2bf(p10.z); a1[3] = (short)f2bf(p10.w);
        a1[4] = (short)f2bf(p11.x); a1[5] = (short)f2bf(p11.y);
        a1[6] = (short)f2bf(p11.z); a1[7] = (short)f2bf(p11.w);

#pragma unroll
        for (int nt = 0; nt < 8; ++nt) {
            const short8 b = *(const short8*)(kbT + (size_t)(nt * 16 + r) * F_IN
                                              + s * 32 + q * 8);
            acc[0][nt] = __builtin_amdgcn_mfma_f32_16x16x32_bf16(a0, b, acc[0][nt], 0, 0, 0);
            acc[1][nt] = __builtin_amdgcn_mfma_f32_16x16x32_bf16(a1, b, acc[1][nt], 0, 0, 0);
        }
    }

    s1a += __shfl_xor(s1a, 16); s1a += __shfl_xor(s1a, 32);
    s1b += __shfl_xor(s1b, 16); s1b += __shfl_xor(s1b, 32);
    s2a += __shfl_xor(s2a, 16); s2a += __shfl_xor(s2a, 32);
    s2b += __shfl_xor(s2b, 16); s2b += __shfl_xor(s2b, 32);
    if (q == 0) {
        float bb2 = b2p[0], bb3 = b3p[0];
        sa1[m_base + r]      = s1a + bb2;
        sa1[m_base + 16 + r] = s1b + bb2;
        szc[m_base + r].x      = s2a + bb3;   // sa2
        szc[m_base + 16 + r].x = s2b + bb3;
    }

    // epilogue: per-row absmax -> biased-uint8 quantize + scale store
#pragma unroll
    for (int t = 0; t < 2; ++t)
#pragma unroll
        for (int reg = 0; reg < 4; ++reg) {
            float m = 0.f;
#pragma unroll
            for (int nt = 0; nt < 8; ++nt) m = fmaxf(m, fabsf(acc[t][nt][reg]));
            m = fmaxf(m, __shfl_xor(m, 1));
            m = fmaxf(m, __shfl_xor(m, 2));
            m = fmaxf(m, __shfl_xor(m, 4));
            m = fmaxf(m, __shfl_xor(m, 8));
            const int row = m_base + t * 16 + q * 4 + reg;
            const float inv = m > 0.f ? 127.f / m : 0.f;
            if (r == 0) szc[row].y = m * (1.f / 127.f);
#pragma unroll
            for (int nt = 0; nt < 8; ++nt) {
                int iq = (int)rintf(acc[t][nt][reg] * inv);
                valq[(size_t)row * D_OUT + nt * 16 + r] =
                    (unsigned char)(iq + 128);
            }
        }
}

// ---------------------------------------------------------------------------
// Kernel D: fused softmax + SpMM, one wave per row.
//   Phase 1 (coalesced): lane l owns edge s+base+l; loads edge_col/adj
//     wave-coalesced, gathers szc[c]=(sa2,scale) with ONE 8B load, computes
//     ex & scale-folded weight w = ex*scale[c]; accumulates per-lane
//     softmax denominator AND per-lane w-sum (for the +128 bias fixup).
//   Phase 2 (batched issue/consume): shfl column indices and issue ALL
//     (<=16) valq gathers into p[16] registers FIRST (4-iter chunk guards),
//     then consume -> up to 16 gathers in flight per wave vs ~4 before.
//   valq holds biased uint8 (v+128): consume uses v_cvt_f32_ubyte (1 op),
//   corrected at the end by acc -= 128*sum(w).
// ---------------------------------------------------------------------------
__global__ __launch_bounds__(256) void attn_agg_kernel(
    const int* __restrict__ row_ptr, const int* __restrict__ edge_col,
    const float* __restrict__ adj, const float* __restrict__ sa1,
    const float2* __restrict__ szc, const unsigned char* __restrict__ valq,
    const float* __restrict__ bias, float* __restrict__ out) {
    const int lane = threadIdx.x & 63;
    const int g    = lane >> 4;
    const int r    = lane & 15;
    const int row  = blockIdx.x * 4 + (threadIdx.x >> 6);

    const int s   = row_ptr[row];
    const int cnt = row_ptr[row + 1] - s;
    const float sa1r = sa1[row];
    const unsigned char* vbase = valq + r * 8;

    // early, independent: bias for epilogue
    const f32x4* bp = (const f32x4*)(bias + (size_t)row * D_OUT + r * 8);
    f32x4 b0 = __builtin_nontemporal_load(bp);
    f32x4 b1 = __builtin_nontemporal_load(bp + 1);

    float acc[8];
#pragma unroll
    for (int j = 0; j < 8; ++j) acc[j] = 0.f;
    float sum = 0.f, sumw = 0.f;

    for (int base = 0; base < cnt; base += 64) {
        const int n = min(64, cnt - base);

        // ---- phase 1: one lane per edge, wave-coalesced ----
        int c = 0;
        float w = 0.f;
        if (lane < n) {
            const int e = s + base + lane;
            c = __builtin_nontemporal_load(edge_col + e);
            const float a = __builtin_nontemporal_load(adj + e);
            const float2 f2 = szc[c];            // (sa2, scale) in one 8B
            float t = a * (sa1r + f2.x);
            t = fmaxf(t, 0.2f * t);              // leaky_relu(0.2)
            const float ex = __expf(t);
            sum += ex;
            w = ex * f2.y;                       // fold dequant scale
        }
        sumw += w;                               // for +128 bias fixup

        // ---- phase 2a: issue all valq gathers (chunks of 4 k's) ----
        const int nchunk = (n + 15) >> 4;        // 1..4
        uint2 p[16];
#pragma unroll
        for (int ch = 0; ch < 4; ++ch) {
            if (ch < nchunk) {
#pragma unroll
                for (int k4 = 0; k4 < 4; ++k4) {
                    const int k = ch * 4 + k4;
                    const int cc = __shfl(c, k * 4 + g);
                    p[k] = *(const uint2*)(vbase + (size_t)cc * D_OUT);
                }
            }
        }
        // ---- phase 2b: consume ----
#pragma unroll
        for (int ch = 0; ch < 4; ++ch) {
            if (ch < nchunk) {
#pragma unroll
                for (int k4 = 0; k4 < 4; ++k4) {
                    const int k = ch * 4 + k4;
                    const float ww = __shfl(w, k * 4 + g);
                    const uint2 q = p[k];
                    acc[0] += ww * ub(q.x, 0); acc[1] += ww * ub(q.x, 1);
                    acc[2] += ww * ub(q.x, 2); acc[3] += ww * ub(q.x, 3);
                    acc[4] += ww * ub(q.y, 0); acc[5] += ww * ub(q.y, 1);
                    acc[6] += ww * ub(q.y, 2); acc[7] += ww * ub(q.y, 3);
                }
            }
        }
    }

    // denominator + w-sum: full 64-lane reduce (lanes held disjoint edges);
    // acc: cross-group reduce only (groups held disjoint edge subsets).
    sum  += __shfl_xor(sum, 1);  sumw += __shfl_xor(sumw, 1);
    sum  += __shfl_xor(sum, 2);  sumw += __shfl_xor(sumw, 2);
    sum  += __shfl_xor(sum, 4);  sumw += __shfl_xor(sumw, 4);
    sum  += __shfl_xor(sum, 8);  sumw += __shfl_xor(sumw, 8);
#pragma unroll
    for (int o = 16; o < 64; o <<= 1) {
        sum  += __shfl_xor(sum, o);
        sumw += __shfl_xor(sumw, o);
#pragma unroll
        for (int j = 0; j < 8; ++j) acc[j] += __shfl_xor(acc[j], o);
    }
    const float inv  = sum > 0.f ? 1.f / sum : 1.f;
    const float corr = 128.f * sumw;             // undo the +128 bias

    if (g == 0) {
        f32x4 r0, r1;
        r0.x = (acc[0] - corr) * inv + b0.x; r0.y = (acc[1] - corr) * inv + b0.y;
        r0.z = (acc[2] - corr) * inv + b0.z; r0.w = (acc[3] - corr) * inv + b0.w;
        r1.x = (acc[4] - corr) * inv + b1.x; r1.y = (acc[5] - corr) * inv + b1.y;
        r1.z = (acc[6] - corr) * inv + b1.z; r1.w = (acc[7] - corr) * inv + b1.w;
        f32x4* op = (f32x4*)(out + (size_t)row * D_OUT + r * 8);
        __builtin_nontemporal_store(r0, op);
        __builtin_nontemporal_store(r1, op + 1);
    }
}

// ---------------------------------------------------------------------------
extern "C" void kernel_launch(void* const* d_in, const int* in_sizes, int n_in,
                              void* d_out, int out_size, void* d_ws,
                              size_t ws_size, hipStream_t stream) {
    const float* x        = (const float*)d_in[0];
    const float* adj      = (const float*)d_in[1];
    const float* W1       = (const float*)d_in[2];
    const float* w2       = (const float*)d_in[3];
    const float* b2       = (const float*)d_in[4];
    const float* w3       = (const float*)d_in[5];
    const float* b3       = (const float*)d_in[6];
    const float* kern     = (const float*)d_in[7];
    const float* bias     = (const float*)d_in[8];
    const int*   edge_row = (const int*)d_in[9];
    const int*   edge_col = (const int*)d_in[10];
    float* out = (float*)d_out;

    unsigned char* valq = (unsigned char*)d_ws;               // N*128 u8
    float2* szc = (float2*)(valq + (size_t)N_NODES * D_OUT);  // N float2
    float*  sa1 = (float*)(szc + N_NODES);                    // N fp32
    int* row_ptr = (int*)(sa1 + N_NODES);                     // N+1 (pad)
    float* v1 = (float*)(row_ptr + N_NODES + 4);              // 256
    float* v2 = v1 + F_IN;                                    // 256
    unsigned short* kbT = (unsigned short*)(v2 + F_IN);       // 128*256 bf16

    hipLaunchKernelGGL(prep_kernel, dim3(256), dim3(128), 0, stream,
                       W1, w2, w3, kern, v1, v2, kbT);
    hipLaunchKernelGGL(row_ptr_kernel, dim3((N_NODES + 1 + 255) / 256),
                       dim3(256), 0, stream, edge_row, row_ptr);
    hipLaunchKernelGGL(gemm_sa_kernel, dim3((N_NODES / 32 + 3) / 4), dim3(256),
                       0, stream, x, kbT, v1, v2, b2, b3, valq, szc, sa1);
    hipLaunchKernelGGL(attn_agg_kernel, dim3(N_NODES / 4), dim3(256), 0,
                       stream, row_ptr, edge_col, adj, sa1, szc, valq,
                       bias, out);
}

// Round 5
// 339.153 us; speedup vs baseline: 1.1412x; 1.0442x over previous
//
#include <hip/hip_runtime.h>
#include <math.h>

#define N_NODES 100000
#define N_EDGES 3200000
#define F_IN    256
#define D_OUT   128

typedef __attribute__((ext_vector_type(8))) short short8;
typedef __attribute__((ext_vector_type(4))) float f32x4;

__device__ __forceinline__ unsigned short f2bf(float f) {
    unsigned u = __float_as_uint(f);
    unsigned r = (u + 0x7FFFu + ((u >> 16) & 1u)) >> 16;   // RNE
    return (unsigned short)r;
}

__device__ __forceinline__ float dot4(f32x4 a, f32x4 b) {
    return a.x * b.x + a.y * b.y + a.z * b.z + a.w * b.w;
}

// unsigned byte k (0..3) of u, as float -> v_cvt_f32_ubyteN
__device__ __forceinline__ float ub(unsigned u, int k) {
    return (float)((u >> (k * 8)) & 0xffu);
}

// ---------------------------------------------------------------------------
// Kernel A: 256 blocks x 128 threads. Block kk:
//   - kbT[n][kk] = bf16(kern[kk][n])  (coalesced read of kern row kk)
//   - wave 0 computes v1[kk] = W1[kk]@w2, v2[kk] = W1[kk]@w3
// ---------------------------------------------------------------------------
__global__ __launch_bounds__(128) void prep_kernel(
    const float* __restrict__ W1, const float* __restrict__ w2,
    const float* __restrict__ w3, const float* __restrict__ kern,
    float* __restrict__ v1, float* __restrict__ v2,
    unsigned short* __restrict__ kbT) {
    const int kk  = blockIdx.x;    // 0..255
    const int tid = threadIdx.x;   // 0..127
    kbT[(size_t)tid * F_IN + kk] = f2bf(kern[(size_t)kk * D_OUT + tid]);
    if (tid < 64) {
        const float* wr = W1 + (size_t)kk * D_OUT;
        float a = wr[tid], b = wr[tid + 64];
        float s1 = a * w2[tid] + b * w2[tid + 64];
        float s2 = a * w3[tid] + b * w3[tid + 64];
#pragma unroll
        for (int o = 32; o > 0; o >>= 1) {
            s1 += __shfl_xor(s1, o);
            s2 += __shfl_xor(s2, o);
        }
        if (tid == 0) { v1[kk] = s1; v2[kk] = s2; }
    }
}

// ---------------------------------------------------------------------------
// Kernel B: CSR row pointers via binary search over sorted edge_row.
// ---------------------------------------------------------------------------
__global__ void row_ptr_kernel(const int* __restrict__ edge_row,
                               int* __restrict__ row_ptr) {
    int r = blockIdx.x * blockDim.x + threadIdx.x;
    if (r > N_NODES) return;
    int lo = 0, hi = N_EDGES;
    while (lo < hi) {
        int mid = (lo + hi) >> 1;
        if (edge_row[mid] < r) lo = mid + 1; else hi = mid;
    }
    row_ptr[r] = lo;
}

// ---------------------------------------------------------------------------
// Kernel C: bf16 MFMA GEMM; epilogue quantizes value rows to UNSIGNED int8
// (bias +128) with per-row absmax scale; writes fused szc[row]=(sa2,scale).
// ---------------------------------------------------------------------------
__global__ __launch_bounds__(256) void gemm_sa_kernel(
    const float* __restrict__ x, const unsigned short* __restrict__ kbT,
    const float* __restrict__ v1, const float* __restrict__ v2,
    const float* __restrict__ b2p, const float* __restrict__ b3p,
    unsigned char* __restrict__ valq, float2* __restrict__ szc,
    float* __restrict__ sa1) {
    const int wid = blockIdx.x * 4 + (threadIdx.x >> 6);
    const int m_base = wid * 32;
    if (m_base >= N_NODES) return;
    const int lane = threadIdx.x & 63;
    const int r = lane & 15;
    const int q = lane >> 4;

    const f32x4* x0 = (const f32x4*)(x + (size_t)(m_base + r) * F_IN + q * 8);
    const f32x4* x1 = (const f32x4*)(x + (size_t)(m_base + 16 + r) * F_IN + q * 8);

    f32x4 acc[2][8];
#pragma unroll
    for (int t = 0; t < 2; ++t)
#pragma unroll
        for (int nt = 0; nt < 8; ++nt) acc[t][nt] = (f32x4)(0.f);
    float s1a = 0.f, s1b = 0.f, s2a = 0.f, s2b = 0.f;

#pragma unroll 2
    for (int s = 0; s < 8; ++s) {            // K-steps of 32
        f32x4 p00 = __builtin_nontemporal_load(x0 + s * 8);
        f32x4 p01 = __builtin_nontemporal_load(x0 + s * 8 + 1);
        f32x4 p10 = __builtin_nontemporal_load(x1 + s * 8);
        f32x4 p11 = __builtin_nontemporal_load(x1 + s * 8 + 1);
        const f32x4* vp1 = (const f32x4*)(v1 + s * 32 + q * 8);
        const f32x4* vp2 = (const f32x4*)(v2 + s * 32 + q * 8);
        f32x4 va = vp1[0], vb = vp1[1], vc = vp2[0], vd = vp2[1];
        s1a += dot4(p00, va) + dot4(p01, vb);
        s2a += dot4(p00, vc) + dot4(p01, vd);
        s1b += dot4(p10, va) + dot4(p11, vb);
        s2b += dot4(p10, vc) + dot4(p11, vd);

        short8 a0, a1;
        a0[0] = (short)f2bf(p00.x); a0[1] = (short)f2bf(p00.y);
        a0[2] = (short)f2bf(p00.z); a0[3] = (short)f2bf(p00.w);
        a0[4] = (short)f2bf(p01.x); a0[5] = (short)f2bf(p01.y);
        a0[6] = (short)f2bf(p01.z); a0[7] = (short)f2bf(p01.w);
        a1[0] = (short)f2bf(p10.x); a1[1] = (short)f2bf(p10.y);
        a1[2] = (short)f2bf(p10.z); a1[3] = (short)f2bf(p10.w);
        a1[4] = (short)f2bf(p11.x); a1[5] = (short)f2bf(p11.y);
        a1[6] = (short)f2bf(p11.z); a1[7] = (short)f2bf(p11.w);

#pragma unroll
        for (int nt = 0; nt < 8; ++nt) {
            const short8 b = *(const short8*)(kbT + (size_t)(nt * 16 + r) * F_IN
                                              + s * 32 + q * 8);
            acc[0][nt] = __builtin_amdgcn_mfma_f32_16x16x32_bf16(a0, b, acc[0][nt], 0, 0, 0);
            acc[1][nt] = __builtin_amdgcn_mfma_f32_16x16x32_bf16(a1, b, acc[1][nt], 0, 0, 0);
        }
    }

    s1a += __shfl_xor(s1a, 16); s1a += __shfl_xor(s1a, 32);
    s1b += __shfl_xor(s1b, 16); s1b += __shfl_xor(s1b, 32);
    s2a += __shfl_xor(s2a, 16); s2a += __shfl_xor(s2a, 32);
    s2b += __shfl_xor(s2b, 16); s2b += __shfl_xor(s2b, 32);
    if (q == 0) {
        float bb2 = b2p[0], bb3 = b3p[0];
        sa1[m_base + r]      = s1a + bb2;
        sa1[m_base + 16 + r] = s1b + bb2;
        szc[m_base + r].x      = s2a + bb3;   // sa2
        szc[m_base + 16 + r].x = s2b + bb3;
    }

    // epilogue: per-row absmax -> biased-uint8 quantize + scale store
#pragma unroll
    for (int t = 0; t < 2; ++t)
#pragma unroll
        for (int reg = 0; reg < 4; ++reg) {
            float m = 0.f;
#pragma unroll
            for (int nt = 0; nt < 8; ++nt) m = fmaxf(m, fabsf(acc[t][nt][reg]));
            m = fmaxf(m, __shfl_xor(m, 1));
            m = fmaxf(m, __shfl_xor(m, 2));
            m = fmaxf(m, __shfl_xor(m, 4));
            m = fmaxf(m, __shfl_xor(m, 8));
            const int row = m_base + t * 16 + q * 4 + reg;
            const float inv = m > 0.f ? 127.f / m : 0.f;
            if (r == 0) szc[row].y = m * (1.f / 127.f);
#pragma unroll
            for (int nt = 0; nt < 8; ++nt) {
                int iq = (int)rintf(acc[t][nt][reg] * inv);
                valq[(size_t)row * D_OUT + nt * 16 + r] =
                    (unsigned char)(iq + 128);
            }
        }
}

// ---------------------------------------------------------------------------
// Kernel D: fused softmax + SpMM. TWO ADJACENT ROWS PER WAVE, software-
// pipelined so row B's memory latencies hide under row A's compute:
//   - edge ranges of rows 2w,2w+1 are contiguous in CSR -> 4 coalesced
//     phase-1 loads fill nearly all 64 lanes (vs ~50% at one row/wave);
//   - both szc gathers issue before either exp;
//   - valq batches: issue A, issue B, consume A, consume B (8-quad chunks,
//     statically indexed pA/pB registers).
// Fallback loop (rare) for rows with >64 edges keeps correctness.
// ---------------------------------------------------------------------------
__global__ __launch_bounds__(256) void attn_agg_kernel(
    const int* __restrict__ row_ptr, const int* __restrict__ edge_col,
    const float* __restrict__ adj, const float* __restrict__ sa1,
    const float2* __restrict__ szc, const unsigned char* __restrict__ valq,
    const float* __restrict__ bias, float* __restrict__ out) {
    const int lane = threadIdx.x & 63;
    const int g    = lane >> 4;
    const int r    = lane & 15;
    const int rA   = __builtin_amdgcn_readfirstlane(
                         blockIdx.x * 8 + (threadIdx.x >> 6) * 2);
    const int rB   = rA + 1;

    const int sA = row_ptr[rA];
    const int eA = row_ptr[rA + 1];
    const int eB = row_ptr[rA + 2];
    const int cntA = eA - sA, cntB = eB - eA;
    const float sa1A = sa1[rA], sa1B = sa1[rB];
    const unsigned char* vbase = valq + r * 8;

    // ---- phase 1: coalesced edge loads for BOTH rows up front ----
    const int nA = min(cntA, 64), nB = min(cntB, 64);
    int cA = 0, cB = 0;
    float aA = 0.f, aB = 0.f;
    if (lane < nA) {
        cA = __builtin_nontemporal_load(edge_col + sA + lane);
        aA = __builtin_nontemporal_load(adj + sA + lane);
    }
    if (lane < nB) {
        cB = __builtin_nontemporal_load(edge_col + eA + lane);
        aB = __builtin_nontemporal_load(adj + eA + lane);
    }
    // both szc gathers in flight before either exp
    float2 fA, fB;
    fA.x = 0.f; fA.y = 0.f; fB.x = 0.f; fB.y = 0.f;
    if (lane < nA) fA = szc[cA];
    if (lane < nB) fB = szc[cB];

    float sumA = 0.f, wA = 0.f;
    float sumB = 0.f, wB = 0.f;
    if (lane < nA) {
        float t = aA * (sa1A + fA.x);
        t = fmaxf(t, 0.2f * t);
        const float ex = __expf(t);
        sumA = ex; wA = ex * fA.y;
    }
    if (lane < nB) {
        float t = aB * (sa1B + fB.x);
        t = fmaxf(t, 0.2f * t);
        const float ex = __expf(t);
        sumB = ex; wB = ex * fB.y;
    }
    float sumwA = wA, sumwB = wB;

    float accA[8], accB[8];
#pragma unroll
    for (int j = 0; j < 8; ++j) { accA[j] = 0.f; accB[j] = 0.f; }

    // ---- phase 2: batched issue/consume, A/B interleaved ----
    const int qA = (nA + 3) >> 2;      // quads (4 edges each), 0..16
    const int qB = (nB + 3) >> 2;
    uint2 pA[8], pB[8];

    // issue batch0 A then B (up to 32 edges each)
#pragma unroll
    for (int k = 0; k < 8; ++k)
        if (k < qA) {
            const int cc = __shfl(cA, k * 4 + g);
            pA[k] = *(const uint2*)(vbase + (size_t)cc * D_OUT);
        }
#pragma unroll
    for (int k = 0; k < 8; ++k)
        if (k < qB) {
            const int cc = __shfl(cB, k * 4 + g);
            pB[k] = *(const uint2*)(vbase + (size_t)cc * D_OUT);
        }
    // consume A batch0
#pragma unroll
    for (int k = 0; k < 8; ++k)
        if (k < qA) {
            const float ww = __shfl(wA, k * 4 + g);
            const uint2 q = pA[k];
            accA[0] += ww * ub(q.x, 0); accA[1] += ww * ub(q.x, 1);
            accA[2] += ww * ub(q.x, 2); accA[3] += ww * ub(q.x, 3);
            accA[4] += ww * ub(q.y, 0); accA[5] += ww * ub(q.y, 1);
            accA[6] += ww * ub(q.y, 2); accA[7] += ww * ub(q.y, 3);
        }
    // issue A batch1 (reuse pA) if row A has >32 edges
    if (qA > 8) {
#pragma unroll
        for (int k = 8; k < 16; ++k)
            if (k < qA) {
                const int cc = __shfl(cA, k * 4 + g);
                pA[k - 8] = *(const uint2*)(vbase + (size_t)cc * D_OUT);
            }
    }
    // consume B batch0
#pragma unroll
    for (int k = 0; k < 8; ++k)
        if (k < qB) {
            const float ww = __shfl(wB, k * 4 + g);
            const uint2 q = pB[k];
            accB[0] += ww * ub(q.x, 0); accB[1] += ww * ub(q.x, 1);
            accB[2] += ww * ub(q.x, 2); accB[3] += ww * ub(q.x, 3);
            accB[4] += ww * ub(q.y, 0); accB[5] += ww * ub(q.y, 1);
            accB[6] += ww * ub(q.y, 2); accB[7] += ww * ub(q.y, 3);
        }
    // issue B batch1 if needed
    if (qB > 8) {
#pragma unroll
        for (int k = 8; k < 16; ++k)
            if (k < qB) {
                const int cc = __shfl(cB, k * 4 + g);
                pB[k - 8] = *(const uint2*)(vbase + (size_t)cc * D_OUT);
            }
    }
    // consume A batch1
    if (qA > 8) {
#pragma unroll
        for (int k = 8; k < 16; ++k)
            if (k < qA) {
                const float ww = __shfl(wA, k * 4 + g);
                const uint2 q = pA[k - 8];
                accA[0] += ww * ub(q.x, 0); accA[1] += ww * ub(q.x, 1);
                accA[2] += ww * ub(q.x, 2); accA[3] += ww * ub(q.x, 3);
                accA[4] += ww * ub(q.y, 0); accA[5] += ww * ub(q.y, 1);
                accA[6] += ww * ub(q.y, 2); accA[7] += ww * ub(q.y, 3);
            }
    }
    // consume B batch1
    if (qB > 8) {
#pragma unroll
        for (int k = 8; k < 16; ++k)
            if (k < qB) {
                const float ww = __shfl(wB, k * 4 + g);
                const uint2 q = pB[k - 8];
                accB[0] += ww * ub(q.x, 0); accB[1] += ww * ub(q.x, 1);
                accB[2] += ww * ub(q.x, 2); accB[3] += ww * ub(q.x, 3);
                accB[4] += ww * ub(q.y, 0); accB[5] += ww * ub(q.y, 1);
                accB[6] += ww * ub(q.y, 2); accB[7] += ww * ub(q.y, 3);
            }
    }

    // ---- rare fallback: rows with more than 64 edges ----
    if (cntA > 64) {
        for (int base = 64; base < cntA; base += 64) {
            const int n = min(64, cntA - base);
            int c = 0; float w = 0.f;
            if (lane < n) {
                const int e = sA + base + lane;
                c = edge_col[e];
                const float a = adj[e];
                const float2 f2 = szc[c];
                float t = a * (sa1A + f2.x);
                t = fmaxf(t, 0.2f * t);
                const float ex = __expf(t);
                sumA += ex; w = ex * f2.y;
            }
            sumwA += w;
            const int qn = (n + 3) >> 2;
            for (int k = 0; k < qn; ++k) {
                const int cc = __shfl(c, k * 4 + g);
                const float ww = __shfl(w, k * 4 + g);
                const uint2 q = *(const uint2*)(vbase + (size_t)cc * D_OUT);
                accA[0] += ww * ub(q.x, 0); accA[1] += ww * ub(q.x, 1);
                accA[2] += ww * ub(q.x, 2); accA[3] += ww * ub(q.x, 3);
                accA[4] += ww * ub(q.y, 0); accA[5] += ww * ub(q.y, 1);
                accA[6] += ww * ub(q.y, 2); accA[7] += ww * ub(q.y, 3);
            }
        }
    }
    if (cntB > 64) {
        for (int base = 64; base < cntB; base += 64) {
            const int n = min(64, cntB - base);
            int c = 0; float w = 0.f;
            if (lane < n) {
                const int e = eA + base + lane;
                c = edge_col[e];
                const float a = adj[e];
                const float2 f2 = szc[c];
                float t = a * (sa1B + f2.x);
                t = fmaxf(t, 0.2f * t);
                const float ex = __expf(t);
                sumB += ex; w = ex * f2.y;
            }
            sumwB += w;
            const int qn = (n + 3) >> 2;
            for (int k = 0; k < qn; ++k) {
                const int cc = __shfl(c, k * 4 + g);
                const float ww = __shfl(w, k * 4 + g);
                const uint2 q = *(const uint2*)(vbase + (size_t)cc * D_OUT);
                accB[0] += ww * ub(q.x, 0); accB[1] += ww * ub(q.x, 1);
                accB[2] += ww * ub(q.x, 2); accB[3] += ww * ub(q.x, 3);
                accB[4] += ww * ub(q.y, 0); accB[5] += ww * ub(q.y, 1);
                accB[6] += ww * ub(q.y, 2); accB[7] += ww * ub(q.y, 3);
            }
        }
    }

    // ---- epilogue bias loads early: overlap the reduction chain ----
    const f32x4* bpA = (const f32x4*)(bias + (size_t)rA * D_OUT + r * 8);
    const f32x4* bpB = (const f32x4*)(bias + (size_t)rB * D_OUT + r * 8);
    f32x4 bA0, bA1, bB0, bB1;
    if (g == 0) { bA0 = __builtin_nontemporal_load(bpA);
                  bA1 = __builtin_nontemporal_load(bpA + 1); }
    if (g == 1) { bB0 = __builtin_nontemporal_load(bpB);
                  bB1 = __builtin_nontemporal_load(bpB + 1); }

    // ---- reductions ----
    // sums: full 64-lane reduce; acc: cross-group (16/32) only
    sumA += __shfl_xor(sumA, 1);  sumwA += __shfl_xor(sumwA, 1);
    sumA += __shfl_xor(sumA, 2);  sumwA += __shfl_xor(sumwA, 2);
    sumA += __shfl_xor(sumA, 4);  sumwA += __shfl_xor(sumwA, 4);
    sumA += __shfl_xor(sumA, 8);  sumwA += __shfl_xor(sumwA, 8);
    sumB += __shfl_xor(sumB, 1);  sumwB += __shfl_xor(sumwB, 1);
    sumB += __shfl_xor(sumB, 2);  sumwB += __shfl_xor(sumwB, 2);
    sumB += __shfl_xor(sumB, 4);  sumwB += __shfl_xor(sumwB, 4);
    sumB += __shfl_xor(sumB, 8);  sumwB += __shfl_xor(sumwB, 8);
#pragma unroll
    for (int o = 16; o < 64; o <<= 1) {
        sumA += __shfl_xor(sumA, o); sumwA += __shfl_xor(sumwA, o);
        sumB += __shfl_xor(sumB, o); sumwB += __shfl_xor(sumwB, o);
#pragma unroll
        for (int j = 0; j < 8; ++j) {
            accA[j] += __shfl_xor(accA[j], o);
            accB[j] += __shfl_xor(accB[j], o);
        }
    }

    // ---- epilogue: group 0 stores row A, group 1 stores row B ----
    if (g == 0) {
        const float inv  = sumA > 0.f ? 1.f / sumA : 1.f;
        const float corr = 128.f * sumwA;
        f32x4 r0, r1;
        r0.x = (accA[0] - corr) * inv + bA0.x; r0.y = (accA[1] - corr) * inv + bA0.y;
        r0.z = (accA[2] - corr) * inv + bA0.z; r0.w = (accA[3] - corr) * inv + bA0.w;
        r1.x = (accA[4] - corr) * inv + bA1.x; r1.y = (accA[5] - corr) * inv + bA1.y;
        r1.z = (accA[6] - corr) * inv + bA1.z; r1.w = (accA[7] - corr) * inv + bA1.w;
        f32x4* op = (f32x4*)(out + (size_t)rA * D_OUT + r * 8);
        __builtin_nontemporal_store(r0, op);
        __builtin_nontemporal_store(r1, op + 1);
    } else if (g == 1) {
        const float inv  = sumB > 0.f ? 1.f / sumB : 1.f;
        const float corr = 128.f * sumwB;
        f32x4 r0, r1;
        r0.x = (accB[0] - corr) * inv + bB0.x; r0.y = (accB[1] - corr) * inv + bB0.y;
        r0.z = (accB[2] - corr) * inv + bB0.z; r0.w = (accB[3] - corr) * inv + bB0.w;
        r1.x = (accB[4] - corr) * inv + bB1.x; r1.y = (accB[5] - corr) * inv + bB1.y;
        r1.z = (accB[6] - corr) * inv + bB1.z; r1.w = (accB[7] - corr) * inv + bB1.w;
        f32x4* op = (f32x4*)(out + (size_t)rB * D_OUT + r * 8);
        __builtin_nontemporal_store(r0, op);
        __builtin_nontemporal_store(r1, op + 1);
    }
}

// ---------------------------------------------------------------------------
extern "C" void kernel_launch(void* const* d_in, const int* in_sizes, int n_in,
                              void* d_out, int out_size, void* d_ws,
                              size_t ws_size, hipStream_t stream) {
    const float* x        = (const float*)d_in[0];
    const float* adj      = (const float*)d_in[1];
    const float* W1       = (const float*)d_in[2];
    const float* w2       = (const float*)d_in[3];
    const float* b2       = (const float*)d_in[4];
    const float* w3       = (const float*)d_in[5];
    const float* b3       = (const float*)d_in[6];
    const float* kern     = (const float*)d_in[7];
    const float* bias     = (const float*)d_in[8];
    const int*   edge_row = (const int*)d_in[9];
    const int*   edge_col = (const int*)d_in[10];
    float* out = (float*)d_out;

    unsigned char* valq = (unsigned char*)d_ws;               // N*128 u8
    float2* szc = (float2*)(valq + (size_t)N_NODES * D_OUT);  // N float2
    float*  sa1 = (float*)(szc + N_NODES);                    // N fp32
    int* row_ptr = (int*)(sa1 + N_NODES);                     // N+1 (pad)
    float* v1 = (float*)(row_ptr + N_NODES + 4);              // 256
    float* v2 = v1 + F_IN;                                    // 256
    unsigned short* kbT = (unsigned short*)(v2 + F_IN);       // 128*256 bf16

    hipLaunchKernelGGL(prep_kernel, dim3(256), dim3(128), 0, stream,
                       W1, w2, w3, kern, v1, v2, kbT);
    hipLaunchKernelGGL(row_ptr_kernel, dim3((N_NODES + 1 + 255) / 256),
                       dim3(256), 0, stream, edge_row, row_ptr);
    hipLaunchKernelGGL(gemm_sa_kernel, dim3((N_NODES / 32 + 3) / 4), dim3(256),
                       0, stream, x, kbT, v1, v2, b2, b3, valq, szc, sa1);
    hipLaunchKernelGGL(attn_agg_kernel, dim3(N_NODES / 8), dim3(256), 0,
                       stream, row_ptr, edge_col, adj, sa1, szc, valq,
                       bias, out);
}